// Round 1
// baseline (261.580 us; speedup 1.0000x reference)
//
#include <hip/hip_runtime.h>
#include <math.h>

#define BN 32
#define SN 256

// One block per batch sample. Thread j owns prediction column j.
// Solves the transposed LSAP: rows = valid GT slots (ngt <= 256), cols = 256 preds.
__global__ __launch_bounds__(256) void detr_match_kernel(
    const float* __restrict__ pred_strokes,   // [B,S,10]
    const float* __restrict__ pred_validity,  // [B,S,1]
    const float* __restrict__ targets,        // [B,S,11]
    float* __restrict__ loss_b)               // [B] workspace
{
    const int b   = blockIdx.x;
    const int tid = threadIdx.x;

    __shared__ float  sPred[SN * 10];   // pred strokes
    __shared__ float  sTarg[SN * 11];   // targets (strokes + validity)
    __shared__ double u[SN], v[SN], sp[SN];
    __shared__ int    path[SN], row4col[SN], col4row[SN], cols[SN];
    __shared__ unsigned char SR[SN], SC[SN];
    __shared__ int    s_ngt, s_i, s_sink;
    __shared__ double s_minval;
    __shared__ double redV[4];
    __shared__ int    redI[4];
    __shared__ float  lred[12];

    // ---- stage inputs to LDS (coalesced) ----
    for (int k = tid; k < SN * 10; k += 256) sPred[k] = pred_strokes[b * SN * 10 + k];
    for (int k = tid; k < SN * 11; k += 256) sTarg[k] = targets[b * SN * 11 + k];
    u[tid] = 0.0; v[tid] = 0.0;
    row4col[tid] = -1; col4row[tid] = -1;
    __syncthreads();

    // ---- valid GT column list (ascending) ----
    if (tid == 0) {
        int n = 0;
        for (int j = 0; j < SN; ++j)
            if (sTarg[j * 11 + 10] > 0.5f) cols[n++] = j;
        s_ngt = n;
    }
    __syncthreads();
    const int ngt = s_ngt;

    const double INF = INFINITY;

    // ---- JV shortest augmenting path, one row at a time ----
    for (int cur = 0; cur < ngt; ++cur) {
        sp[tid] = INF;
        SC[tid] = 0;
        SR[tid] = 0;
        if (tid == 0) { s_i = cur; s_sink = -1; s_minval = 0.0; }
        __syncthreads();

        while (true) {
            const int    i    = s_i;
            const double minv = s_minval;
            if (tid == 0) SR[i] = 1;

            // relax: r = ((min_val + cost[i][tid]) - u[i]) - v[tid]
            double cand;
            if (!SC[tid]) {
                const int g = cols[i];
                const float* pp = &sPred[tid * 10];
                const float* gg = &sTarg[g * 11];
                float c = 0.f;
                #pragma unroll
                for (int d = 0; d < 8; ++d) c += fabsf(pp[d] - gg[d]);
                float w = fabsf(pp[8] - gg[8]) + fabsf(pp[9] - gg[9]);
                float cf = 5.0f * c + w;
                double r = ((minv + (double)cf) - u[i]) - v[tid];
                if (r < sp[tid]) { sp[tid] = r; path[tid] = i; }
                cand = sp[tid];
            } else {
                cand = INF;
            }

            // wave-level argmin (value, index), tie -> lowest index
            double bv = cand;
            int    bi = tid;
            #pragma unroll
            for (int off = 32; off > 0; off >>= 1) {
                double ov = __shfl_down(bv, off, 64);
                int    oi = __shfl_down(bi, off, 64);
                if (ov < bv || (ov == bv && oi < bi)) { bv = ov; bi = oi; }
            }
            if ((tid & 63) == 0) { redV[tid >> 6] = bv; redI[tid >> 6] = bi; }
            __syncthreads();

            if (tid == 0) {
                double best = redV[0]; int bj = redI[0];
                #pragma unroll
                for (int w = 1; w < 4; ++w) {
                    if (redV[w] < best || (redV[w] == best && redI[w] < bj)) {
                        best = redV[w]; bj = redI[w];
                    }
                }
                s_minval = best;
                if (row4col[bj] == -1) {
                    s_sink = bj;               // unmatched column -> augmenting path ends
                } else {
                    s_i = row4col[bj];         // continue from the row matched to bj
                    SC[bj] = 1;                // remove bj from remaining
                }
            }
            __syncthreads();
            if (s_sink != -1) break;
        }

        // ---- dual updates (before augmentation, as in reference) ----
        const double minv = s_minval;
        if (tid < ngt && SR[tid]) {
            if (tid == cur) u[tid] += minv;
            else            u[tid] += minv - sp[col4row[tid]];
        }
        if (SC[tid]) v[tid] += sp[tid] - minv;
        __syncthreads();

        // ---- augment along path (sequential, thread 0) ----
        if (tid == 0) {
            int j = s_sink;
            while (true) {
                int i2 = path[j];
                row4col[j] = i2;
                int tmp = col4row[i2];
                col4row[i2] = j;
                j = tmp;
                if (i2 == cur) break;
            }
        }
        __syncthreads();
    }

    // ---- loss ----
    float coordv = 0.f, widthv = 0.f;
    if (tid < ngt) {
        const int p = col4row[tid];      // matched prediction for GT slot tid
        const int g = cols[tid];         // actual GT column
        const float* pp = &sPred[p * 10];
        const float* gg = &sTarg[g * 11];
        float c = 0.f;
        #pragma unroll
        for (int d = 0; d < 8; ++d) c += fabsf(pp[d] - gg[d]);
        coordv = c;
        widthv = fabsf(pp[8] - gg[8]) + fabsf(pp[9] - gg[9]);
    }
    // BCE for position tid
    float pv  = pred_validity[b * SN + tid];
    float t   = sTarg[tid * 11 + 10];
    float lp  = logf(pv);        if (lp  < -100.f) lp  = -100.f;
    float l1p = logf(1.f - pv);  if (l1p < -100.f) l1p = -100.f;
    float bce = -(t * lp + (1.f - t) * l1p);

    float cs = coordv, ws = widthv, bs = bce;
    #pragma unroll
    for (int off = 32; off > 0; off >>= 1) {
        cs += __shfl_down(cs, off, 64);
        ws += __shfl_down(ws, off, 64);
        bs += __shfl_down(bs, off, 64);
    }
    if ((tid & 63) == 0) {
        lred[(tid >> 6) * 3 + 0] = cs;
        lred[(tid >> 6) * 3 + 1] = ws;
        lred[(tid >> 6) * 3 + 2] = bs;
    }
    __syncthreads();
    if (tid == 0) {
        float C = 0.f, W = 0.f, Bc = 0.f;
        #pragma unroll
        for (int w = 0; w < 4; ++w) {
            C  += lred[w * 3 + 0];
            W  += lred[w * 3 + 1];
            Bc += lred[w * 3 + 2];
        }
        float bcem = Bc / (float)SN;
        float lb;
        if (ngt > 0) lb = 5.f * C / (8.f * (float)ngt) + W / (2.f * (float)ngt) + bcem;
        else         lb = bcem;
        loss_b[b] = lb;
    }
}

__global__ void detr_finalize_kernel(const float* __restrict__ loss_b,
                                     float* __restrict__ out)
{
    if (threadIdx.x == 0) {
        float s = 0.f;
        for (int b = 0; b < BN; ++b) s += loss_b[b];
        out[0] = s / (float)BN;
    }
}

extern "C" void kernel_launch(void* const* d_in, const int* in_sizes, int n_in,
                              void* d_out, int out_size, void* d_ws, size_t ws_size,
                              hipStream_t stream) {
    const float* pred_strokes  = (const float*)d_in[0];
    const float* pred_validity = (const float*)d_in[1];
    const float* targets       = (const float*)d_in[2];
    float* out    = (float*)d_out;
    float* loss_b = (float*)d_ws;   // 32 floats of scratch

    detr_match_kernel<<<BN, 256, 0, stream>>>(pred_strokes, pred_validity, targets, loss_b);
    detr_finalize_kernel<<<1, 64, 0, stream>>>(loss_b, out);
}

// Round 2
// 215.205 us; speedup vs baseline: 1.2155x; 1.2155x over previous
//
#include <hip/hip_runtime.h>
#include <math.h>

#define BN 32
#define SN 256

// Sortable-key transform for doubles (exact total order; monotone increasing).
__device__ __forceinline__ unsigned long long d2k(double d) {
    unsigned long long b = (unsigned long long)__double_as_longlong(d);
    return (b & 0x8000000000000000ull) ? ~b : (b | 0x8000000000000000ull);
}
__device__ __forceinline__ double k2d(unsigned long long k) {
    unsigned long long b = (k & 0x8000000000000000ull) ? (k ^ 0x8000000000000000ull) : ~k;
    return __longlong_as_double((long long)b);
}

// One WAVE (64 lanes) per batch sample. Lane L owns prediction columns L*4..L*4+3.
// Solves the transposed LSAP: rows = valid GT slots (ngt<=256), cols = 256 preds.
// Hot loop has NO barriers: single-wave lockstep + shuffles/ballots only.
__global__ __launch_bounds__(64) void detr_match_kernel(
    const float* __restrict__ pred_strokes,   // [B,S,10]
    const float* __restrict__ pred_validity,  // [B,S,1]
    const float* __restrict__ targets,        // [B,S,11]
    float* __restrict__ loss_b)               // [B]
{
    const int b    = blockIdx.x;
    const int lane = threadIdx.x;   // 0..63

    __shared__ __align__(16) float sPred[SN * 10];
    __shared__ __align__(16) float sTarg[SN * 11];
    __shared__ __align__(16) float sRow[SN * 12];   // compacted GT rows: 10 coords + u (double) at +10
    __shared__ int colsL[SN];
    __shared__ int row4col[SN];
    __shared__ int col4row[SN];
    __shared__ int pathL[SN];

    // ---- stage inputs (float4-coalesced) ----
    {
        const float4* gp  = (const float4*)(pred_strokes + (size_t)b * SN * 10);
        float4*       sp4 = (float4*)sPred;
        #pragma unroll
        for (int t = 0; t < 10; ++t) sp4[lane + 64 * t] = gp[lane + 64 * t];
        const float4* gt  = (const float4*)(targets + (size_t)b * SN * 11);
        float4*       st4 = (float4*)sTarg;
        #pragma unroll
        for (int t = 0; t < 11; ++t) st4[lane + 64 * t] = gt[lane + 64 * t];
        ((int4*)row4col)[lane] = make_int4(-1, -1, -1, -1);
        ((int4*)col4row)[lane] = make_int4(-1, -1, -1, -1);
    }
    __syncthreads();

    // ---- valid GT column list (ascending) via ballot prefix; ngt uniform in regs ----
    int ngt = 0;
    #pragma unroll
    for (int s = 0; s < 4; ++s) {
        int  pos = s * 64 + lane;
        bool val = sTarg[pos * 11 + 10] > 0.5f;
        unsigned long long m = __ballot(val);
        if (val) colsL[ngt + (int)__popcll(m & ((1ull << lane) - 1ull))] = pos;
        ngt += (int)__popcll(m);
    }

    // ---- compact GT rows (stride 12 floats; dual u inlined as double at +10) ----
    for (int r = lane; r < ngt; r += 64) {
        int g = colsL[r];
        #pragma unroll
        for (int d = 0; d < 10; ++d) sRow[r * 12 + d] = sTarg[g * 11 + d];
        *reinterpret_cast<double*>(&sRow[r * 12 + 10]) = 0.0;
    }
    __syncthreads();

    // ---- own 4 pred rows to registers ----
    float pr[4][10];
    #pragma unroll
    for (int s = 0; s < 4; ++s)
        #pragma unroll
        for (int d = 0; d < 10; ++d)
            pr[s][d] = sPred[(lane * 4 + s) * 10 + d];

    double v[4] = {0.0, 0.0, 0.0, 0.0};   // column duals, register-resident

    for (int cur = 0; cur < ngt; ++cur) {
        double sp[4]  = {INFINITY, INFINITY, INFINITY, INFINITY};
        unsigned long long key[4] = {0xFFF0000000000000ull, 0xFFF0000000000000ull,
                                     0xFFF0000000000000ull, 0xFFF0000000000000ull};
        int    pth[4] = {cur, cur, cur, cur};
        int    scm    = 0;          // SC bits for this lane's 4 columns
        double minv   = 0.0;
        int    i      = cur;
        int    sink;

        for (;;) {
            // row i: 10 coords + dual u, one base address
            const float* rp = &sRow[i * 12];
            float  gc[10];
            #pragma unroll
            for (int d = 0; d < 10; ++d) gc[d] = rp[d];
            double ui = *reinterpret_cast<const double*>(rp + 10);

            // relax this lane's non-SC columns (exact reference arithmetic/order)
            #pragma unroll
            for (int s = 0; s < 4; ++s) {
                if (!(scm & (1 << s))) {
                    float c = 0.f;
                    #pragma unroll
                    for (int d = 0; d < 8; ++d) c += fabsf(pr[s][d] - gc[d]);
                    float w  = fabsf(pr[s][8] - gc[8]) + fabsf(pr[s][9] - gc[9]);
                    float cf = 5.0f * c + w;
                    double r = ((minv + (double)cf) - ui) - v[s];
                    if (r < sp[s]) { sp[s] = r; key[s] = d2k(r); pth[s] = i; }
                }
            }

            // in-lane min over 4 keys (SC keys are UMAX, strictly above any sp)
            unsigned long long bk = key[0];
            if (key[1] < bk) bk = key[1];
            if (key[2] < bk) bk = key[2];
            if (key[3] < bk) bk = key[3];

            // 5-step butterfly within 32-lane halves, then readlane(0)/readlane(32)
            #pragma unroll
            for (int m = 1; m <= 16; m <<= 1) {
                unsigned long long o = __shfl_xor(bk, m, 64);
                if (o < bk) bk = o;
            }
            unsigned int blo = (unsigned int)bk, bhi = (unsigned int)(bk >> 32);
            unsigned long long k0 =
                ((unsigned long long)(unsigned int)__builtin_amdgcn_readlane((int)bhi, 0) << 32) |
                (unsigned int)__builtin_amdgcn_readlane((int)blo, 0);
            unsigned long long k1 =
                ((unsigned long long)(unsigned int)__builtin_amdgcn_readlane((int)bhi, 32) << 32) |
                (unsigned int)__builtin_amdgcn_readlane((int)blo, 32);
            unsigned long long minK = (k1 < k0) ? k1 : k0;

            // winner = lowest column with key==minK (numpy first-occurrence tie-break)
            unsigned long long m0 = __ballot(key[0] == minK);
            unsigned long long m1 = __ballot(key[1] == minK);
            unsigned long long m2 = __ballot(key[2] == minK);
            unsigned long long m3 = __ballot(key[3] == minK);
            int l0 = m0 ? __builtin_ctzll(m0) : 64;
            int l1 = m1 ? __builtin_ctzll(m1) : 64;
            int l2 = m2 ? __builtin_ctzll(m2) : 64;
            int l3 = m3 ? __builtin_ctzll(m3) : 64;
            int lm = l0 < l1 ? l0 : l1;
            int lmb = l2 < l3 ? l2 : l3;
            if (lmb < lm) lm = lmb;
            int slot = (l0 == lm) ? 0 : (l1 == lm) ? 1 : (l2 == lm) ? 2 : 3;
            int bj   = lm * 4 + slot;

            minv = k2d(minK);
            int rn = row4col[bj];            // broadcast LDS read
            if (rn < 0) { sink = bj; break; }
            i = rn;
            if ((bj >> 2) == lane) {         // owner removes bj from remaining
                int s2 = bj & 3;
                scm |= (1 << s2);
                key[s2] = 0xFFFFFFFFFFFFFFFFull;
            }
        }

        // ---- dual updates (before augmentation). SR rows == {cur} ∪ row4col[SC]. ----
        if (lane == 0)
            *reinterpret_cast<double*>(&sRow[cur * 12 + 10]) += minv;
        #pragma unroll
        for (int s = 0; s < 4; ++s) {
            if (scm & (1 << s)) {
                int c  = lane * 4 + s;
                int rj = row4col[c];         // matched row of this SC column (pre-augment)
                *reinterpret_cast<double*>(&sRow[rj * 12 + 10]) += minv - sp[s];
                v[s] += sp[s] - minv;
            }
        }
        // path: all 4 slots were refreshed at step 1 of this row
        ((int4*)pathL)[lane] = make_int4(pth[0], pth[1], pth[2], pth[3]);

        // ---- augment (serial walk, lane 0) ----
        if (lane == 0) {
            int j = sink;
            for (;;) {
                int i2 = pathL[j];
                row4col[j] = i2;
                int tmp = col4row[i2];
                col4row[i2] = j;
                j = tmp;
                if (i2 == cur) break;
            }
        }
        __syncthreads();   // single wave: compiles to a cheap waitcnt(+barrier); once per row
    }

    // ---- loss ----
    float coordv = 0.f, widthv = 0.f;
    #pragma unroll
    for (int s = 0; s < 4; ++s) {
        int r = lane * 4 + s;
        if (r < ngt) {
            int p = col4row[r];
            int g = colsL[r];
            const float* pp = &sPred[p * 10];
            const float* gg = &sTarg[g * 11];
            float c = 0.f;
            #pragma unroll
            for (int d = 0; d < 8; ++d) c += fabsf(pp[d] - gg[d]);
            coordv += c;
            widthv += fabsf(pp[8] - gg[8]) + fabsf(pp[9] - gg[9]);
        }
    }
    float bces = 0.f;
    {
        const float4 pv = ((const float4*)(pred_validity + (size_t)b * SN))[lane];
        const float pvs[4] = {pv.x, pv.y, pv.z, pv.w};
        #pragma unroll
        for (int s = 0; s < 4; ++s) {
            float t   = sTarg[(lane * 4 + s) * 11 + 10];
            float p   = pvs[s];
            float lp  = logf(p);       if (lp  < -100.f) lp  = -100.f;
            float l1p = logf(1.f - p); if (l1p < -100.f) l1p = -100.f;
            bces += -(t * lp + (1.f - t) * l1p);
        }
    }
    #pragma unroll
    for (int m = 1; m <= 32; m <<= 1) {
        coordv += __shfl_xor(coordv, m, 64);
        widthv += __shfl_xor(widthv, m, 64);
        bces   += __shfl_xor(bces,   m, 64);
    }
    if (lane == 0) {
        float bcem = bces / (float)SN;
        float lb = (ngt > 0)
                 ? (5.f * coordv / (8.f * (float)ngt) + widthv / (2.f * (float)ngt) + bcem)
                 : bcem;
        loss_b[b] = lb;
    }
}

__global__ __launch_bounds__(64) void detr_finalize_kernel(
    const float* __restrict__ loss_b, float* __restrict__ out)
{
    int lane = threadIdx.x;
    float x = (lane < BN) ? loss_b[lane] : 0.f;
    #pragma unroll
    for (int m = 1; m <= 32; m <<= 1) x += __shfl_xor(x, m, 64);
    if (lane == 0) out[0] = x / (float)BN;
}

extern "C" void kernel_launch(void* const* d_in, const int* in_sizes, int n_in,
                              void* d_out, int out_size, void* d_ws, size_t ws_size,
                              hipStream_t stream) {
    const float* pred_strokes  = (const float*)d_in[0];
    const float* pred_validity = (const float*)d_in[1];
    const float* targets       = (const float*)d_in[2];
    float* out    = (float*)d_out;
    float* loss_b = (float*)d_ws;

    detr_match_kernel<<<BN, 64, 0, stream>>>(pred_strokes, pred_validity, targets, loss_b);
    detr_finalize_kernel<<<1, 64, 0, stream>>>(loss_b, out);
}

// Round 3
// 165.554 us; speedup vs baseline: 1.5800x; 1.2999x over previous
//
#include <hip/hip_runtime.h>
#include <math.h>

#define BN 32
#define SN 256

#define KINF 0xFF800000u   // f2k(+inf)
#define KMAX 0xFFFFFFFFu   // SC sentinel (> any finite key)

// Sortable-key transform for f32 (monotone, total order on non-NaN).
__device__ __forceinline__ unsigned f2k(float f) {
    unsigned b = __float_as_uint(f);
    return (b & 0x80000000u) ? ~b : (b | 0x80000000u);
}
__device__ __forceinline__ float k2f(unsigned k) {
    unsigned b = (k & 0x80000000u) ? (k ^ 0x80000000u) : ~k;
    return __uint_as_float(b);
}
// Select among 4 per-lane registers by uniform slot index (no dynamic indexing).
__device__ __forceinline__ int sel4(int a0, int a1, int a2, int a3, int s) {
    int x01 = (s & 1) ? a1 : a0;
    int x23 = (s & 1) ? a3 : a2;
    return (s & 2) ? x23 : x01;
}

// DPP min step: pure-VALU cross-lane (no LDS). bound_ctrl=false + old=x keeps
// own value where the source lane is invalid.
#define DPP_MIN(x, ctrl) do {                                                   \
    unsigned _t = (unsigned)__builtin_amdgcn_update_dpp((int)(x), (int)(x),     \
                                                        (ctrl), 0xF, 0xF, false);\
    if (_t < (x)) (x) = _t;                                                     \
} while (0)

// One WAVE per batch sample; lane L owns prediction columns 4L..4L+3.
// Hot loop: zero LDS writes, one broadcast LDS read (row coords + dual u),
// everything else registers/DPP/ballots.
__global__ __launch_bounds__(64) void detr_match_kernel(
    const float* __restrict__ pred_strokes,   // [B,S,10]
    const float* __restrict__ pred_validity,  // [B,S,1]
    const float* __restrict__ targets,        // [B,S,11]
    float* __restrict__ loss_b)               // [B]
{
    const int b    = blockIdx.x;
    const int lane = threadIdx.x;

    __shared__ __align__(16) float sPred[SN * 10];
    __shared__ __align__(16) float sTarg[SN * 11];
    __shared__ __align__(16) float sRow[SN * 12];   // 10 coords + dual u at +10
    __shared__ int colsL[SN];

    // ---- stage inputs (float4-coalesced) ----
    {
        const float4* gp  = (const float4*)(pred_strokes + (size_t)b * SN * 10);
        float4*       sp4 = (float4*)sPred;
        #pragma unroll
        for (int t = 0; t < 10; ++t) sp4[lane + 64 * t] = gp[lane + 64 * t];
        const float4* gt  = (const float4*)(targets + (size_t)b * SN * 11);
        float4*       st4 = (float4*)sTarg;
        #pragma unroll
        for (int t = 0; t < 11; ++t) st4[lane + 64 * t] = gt[lane + 64 * t];
    }
    __syncthreads();

    // ---- valid GT list (ascending) via ballot prefix ----
    int ngt = 0;
    #pragma unroll
    for (int s = 0; s < 4; ++s) {
        int  pos = s * 64 + lane;
        bool val = sTarg[pos * 11 + 10] > 0.5f;
        unsigned long long m = __ballot(val);
        if (val) colsL[ngt + (int)__popcll(m & ((1ull << lane) - 1ull))] = pos;
        ngt += (int)__popcll(m);
    }
    __syncthreads();

    // ---- compact GT rows; dual u inlined at +10 ----
    for (int r = lane; r < ngt; r += 64) {
        int g = colsL[r];
        #pragma unroll
        for (int d = 0; d < 10; ++d) sRow[r * 12 + d] = sTarg[g * 11 + d];
        sRow[r * 12 + 10] = 0.f;
    }
    __syncthreads();

    // ---- own 4 pred rows to registers ----
    float pr[4][10];
    #pragma unroll
    for (int s = 0; s < 4; ++s)
        #pragma unroll
        for (int d = 0; d < 10; ++d)
            pr[s][d] = sPred[(lane * 4 + s) * 10 + d];

    // Distributed state: columns 4L+s -> lane L slot s; rows 4L+s -> lane L slot s.
    float v0 = 0.f, v1 = 0.f, v2 = 0.f, v3 = 0.f;          // column duals
    int   rv0 = -1, rv1 = -1, rv2 = -1, rv3 = -1;          // row4col
    int   cr0 = -1, cr1 = -1, cr2 = -1, cr3 = -1;          // col4row
    int   p0 = -1, p1 = -1, p2 = -1, p3 = -1;              // path
    float sc0 = 0.f, sc1 = 0.f, sc2 = 0.f, sc3 = 0.f;      // sp at SC-entry

    for (int cur = 0; cur < ngt; ++cur) {
        unsigned k0 = KINF, k1 = KINF, k2 = KINF, k3 = KINF;
        int   scm  = 0;
        float minv = 0.f;
        int   i    = cur;
        int   sink;

        for (;;) {
            const float* rp = &sRow[i * 12];
            float gc[10];
            #pragma unroll
            for (int d = 0; d < 10; ++d) gc[d] = rp[d];
            float ui = rp[10];

            #define RELAX(S, KS, PS, VS)                                         \
            {                                                                    \
                float c = 0.f;                                                   \
                _Pragma("unroll")                                                \
                for (int d = 0; d < 8; ++d) c += fabsf(pr[S][d] - gc[d]);        \
                float w  = fabsf(pr[S][8] - gc[8]) + fabsf(pr[S][9] - gc[9]);    \
                float r  = ((minv + (5.0f * c + w)) - ui) - VS;                  \
                unsigned kr = f2k(r);                                            \
                bool upd = (kr < KS) && !((scm >> S) & 1);                       \
                if (upd) { KS = kr; PS = i; }                                    \
            }
            RELAX(0, k0, p0, v0)
            RELAX(1, k1, p1, v1)
            RELAX(2, k2, p2, v2)
            RELAX(3, k3, p3, v3)
            #undef RELAX

            unsigned bk = k0 < k1 ? k0 : k1;
            unsigned bc = k2 < k3 ? k2 : k3;
            if (bc < bk) bk = bc;
            DPP_MIN(bk, 0x111);  // row_shr:1
            DPP_MIN(bk, 0x112);  // row_shr:2
            DPP_MIN(bk, 0x114);  // row_shr:4
            DPP_MIN(bk, 0x118);  // row_shr:8
            DPP_MIN(bk, 0x142);  // row_bcast:15
            DPP_MIN(bk, 0x143);  // row_bcast:31
            unsigned minK = (unsigned)__builtin_amdgcn_readlane((int)bk, 63);

            // winner = lowest column with key==minK (first-occurrence tie-break)
            unsigned long long m0 = __ballot(k0 == minK);
            unsigned long long m1 = __ballot(k1 == minK);
            unsigned long long m2 = __ballot(k2 == minK);
            unsigned long long m3 = __ballot(k3 == minK);
            int l0 = m0 ? __builtin_ctzll(m0) : 64;
            int l1 = m1 ? __builtin_ctzll(m1) : 64;
            int l2 = m2 ? __builtin_ctzll(m2) : 64;
            int l3 = m3 ? __builtin_ctzll(m3) : 64;
            int lm  = l0 < l1 ? l0 : l1;
            int lmb = l2 < l3 ? l2 : l3;
            if (lmb < lm) lm = lmb;
            int slot = (l0 == lm) ? 0 : (l1 == lm) ? 1 : (l2 == lm) ? 2 : 3;
            int bj   = lm * 4 + slot;

            minv = k2f(minK);

            int rn = __builtin_amdgcn_readlane(sel4(rv0, rv1, rv2, rv3, slot), lm);
            if (rn < 0) { sink = bj; break; }
            i = rn;

            bool own = (lane == lm);
            switch (slot) {
                case 0:  if (own) { scm |= 1; k0 = KMAX; sc0 = minv; } break;
                case 1:  if (own) { scm |= 2; k1 = KMAX; sc1 = minv; } break;
                case 2:  if (own) { scm |= 4; k2 = KMAX; sc2 = minv; } break;
                default: if (own) { scm |= 8; k3 = KMAX; sc3 = minv; } break;
            }
        }

        // ---- dual updates (before augmentation) ----
        if (lane == 0) sRow[cur * 12 + 10] += minv;
        if (scm & 1) { sRow[rv0 * 12 + 10] += minv - sc0; v0 += sc0 - minv; }
        if (scm & 2) { sRow[rv1 * 12 + 10] += minv - sc1; v1 += sc1 - minv; }
        if (scm & 4) { sRow[rv2 * 12 + 10] += minv - sc2; v2 += sc2 - minv; }
        if (scm & 8) { sRow[rv3 * 12 + 10] += minv - sc3; v3 += sc3 - minv; }

        // ---- augment: wave-uniform register walk ----
        int j = sink;
        for (;;) {
            int sj = j & 3, lj = j >> 2;
            int i2 = __builtin_amdgcn_readlane(sel4(p0, p1, p2, p3, sj), lj);
            bool ownj = (lane == lj);
            switch (sj) {
                case 0:  if (ownj) rv0 = i2; break;
                case 1:  if (ownj) rv1 = i2; break;
                case 2:  if (ownj) rv2 = i2; break;
                default: if (ownj) rv3 = i2; break;
            }
            int si = i2 & 3, li = i2 >> 2;
            int tmp = __builtin_amdgcn_readlane(sel4(cr0, cr1, cr2, cr3, si), li);
            bool owni = (lane == li);
            switch (si) {
                case 0:  if (owni) cr0 = j; break;
                case 1:  if (owni) cr1 = j; break;
                case 2:  if (owni) cr2 = j; break;
                default: if (owni) cr3 = j; break;
            }
            j = tmp;
            if (i2 == cur) break;
        }
        __syncthreads();   // order the scattered u-writes before next round's reads
    }

    // ---- loss ----
    float coordv = 0.f, widthv = 0.f;
    #pragma unroll
    for (int s = 0; s < 4; ++s) {
        int r = lane * 4 + s;
        if (r < ngt) {
            int p = (s == 0) ? cr0 : (s == 1) ? cr1 : (s == 2) ? cr2 : cr3;
            const float* pp = &sPred[p * 10];
            const float* gg = &sRow[r * 12];
            float c = 0.f;
            #pragma unroll
            for (int d = 0; d < 8; ++d) c += fabsf(pp[d] - gg[d]);
            coordv += c;
            widthv += fabsf(pp[8] - gg[8]) + fabsf(pp[9] - gg[9]);
        }
    }
    float bces = 0.f;
    {
        const float4 pv = ((const float4*)(pred_validity + (size_t)b * SN))[lane];
        const float pvs[4] = {pv.x, pv.y, pv.z, pv.w};
        #pragma unroll
        for (int s = 0; s < 4; ++s) {
            float t   = sTarg[(lane * 4 + s) * 11 + 10];
            float p   = pvs[s];
            float lp  = logf(p);       if (lp  < -100.f) lp  = -100.f;
            float l1p = logf(1.f - p); if (l1p < -100.f) l1p = -100.f;
            bces += -(t * lp + (1.f - t) * l1p);
        }
    }
    #pragma unroll
    for (int m = 1; m <= 32; m <<= 1) {
        coordv += __shfl_xor(coordv, m, 64);
        widthv += __shfl_xor(widthv, m, 64);
        bces   += __shfl_xor(bces,   m, 64);
    }
    if (lane == 0) {
        float bcem = bces / (float)SN;
        float lb = (ngt > 0)
                 ? (5.f * coordv / (8.f * (float)ngt) + widthv / (2.f * (float)ngt) + bcem)
                 : bcem;
        loss_b[b] = lb;
    }
}

__global__ __launch_bounds__(64) void detr_finalize_kernel(
    const float* __restrict__ loss_b, float* __restrict__ out)
{
    int lane = threadIdx.x;
    float x = (lane < BN) ? loss_b[lane] : 0.f;
    #pragma unroll
    for (int m = 1; m <= 32; m <<= 1) x += __shfl_xor(x, m, 64);
    if (lane == 0) out[0] = x / (float)BN;
}

extern "C" void kernel_launch(void* const* d_in, const int* in_sizes, int n_in,
                              void* d_out, int out_size, void* d_ws, size_t ws_size,
                              hipStream_t stream) {
    const float* pred_strokes  = (const float*)d_in[0];
    const float* pred_validity = (const float*)d_in[1];
    const float* targets       = (const float*)d_in[2];
    float* out    = (float*)d_out;
    float* loss_b = (float*)d_ws;

    detr_match_kernel<<<BN, 64, 0, stream>>>(pred_strokes, pred_validity, targets, loss_b);
    detr_finalize_kernel<<<1, 64, 0, stream>>>(loss_b, out);
}

// Round 4
// 147.954 us; speedup vs baseline: 1.7680x; 1.1190x over previous
//
#include <hip/hip_runtime.h>
#include <math.h>

#define BN 32
#define SN 256
#define CAP 48            // cached cost rows; CAP*SN*4 + rest stays < 64 KB static LDS

#define KINF 0xFF800000u  // f2k(+inf)
#define KMAX 0xFFFFFFFFu  // SC sentinel (> any finite key)

// Sortable-key transform for f32 (monotone, total order on non-NaN).
__device__ __forceinline__ unsigned f2k(float f) {
    unsigned b = __float_as_uint(f);
    return (b & 0x80000000u) ? ~b : (b | 0x80000000u);
}
__device__ __forceinline__ float k2f(unsigned k) {
    unsigned b = (k & 0x80000000u) ? (k ^ 0x80000000u) : ~k;
    return __uint_as_float(b);
}
__device__ __forceinline__ int sel4(int a0, int a1, int a2, int a3, int s) {
    int x01 = (s & 1) ? a1 : a0;
    int x23 = (s & 1) ? a3 : a2;
    return (s & 2) ? x23 : x01;
}
// DPP min step: pure-VALU cross-lane. Pattern validated in round 3 (lane 63
// ends with the wave-wide min after shr 1/2/4/8 + bcast15 + bcast31).
#define DPP_MIN(x, ctrl) do {                                                    \
    unsigned _t = (unsigned)__builtin_amdgcn_update_dpp((int)(x), (int)(x),      \
                                                        (ctrl), 0xF, 0xF, false);\
    if (_t < (x)) (x) = _t;                                                      \
} while (0)

// L1 cost, exact reference op order: 5*(sum |d0..d7|) + (|d8|+|d9|)
__device__ __forceinline__ float costf(const float* pb, const float* gc) {
    float c = 0.f;
    #pragma unroll
    for (int d = 0; d < 8; ++d) c += fabsf(pb[d] - gc[d]);
    float w = fabsf(pb[8] - gc[8]) + fabsf(pb[9] - gc[9]);
    return 5.0f * c + w;
}

// One WAVE per batch sample; lane L owns prediction columns 4L..4L+3 and
// GT rows 4L..4L+3. JV with greedy row-reduction init + cached cost rows.
__global__ __launch_bounds__(64) void detr_match_kernel(
    const float* __restrict__ pred_strokes,   // [B,S,10]
    const float* __restrict__ pred_validity,  // [B,S,1]
    const float* __restrict__ targets,        // [B,S,11]
    float* __restrict__ loss_b)               // [B]
{
    const int b    = blockIdx.x;
    const int lane = threadIdx.x;

    __shared__ __align__(16) float sCost[CAP * SN];  // cached cost rows (49152 B)
    __shared__ __align__(16) float sRowC[SN * 10];   // compacted GT coords (10240 B)
    __shared__ float sU[SN];                         // row duals
    __shared__ float sVal[SN];                       // GT validity per original position
    __shared__ int   sFree[SN];                      // rows left free after greedy

    // ---- pred rows straight to registers (10x b128 per lane) ----
    __align__(16) float prf[40];                     // prf[s*10+d] = pred[4*lane+s][d]
    {
        const float4* gp = (const float4*)(pred_strokes + (size_t)b * SN * 10 + lane * 40);
        #pragma unroll
        for (int t = 0; t < 10; ++t) ((float4*)prf)[t] = gp[t];
    }
    // ---- targets to LDS temp (reuse sCost region) ----
    float* tmpT = sCost;                             // 256*11 floats = 11264 B < CAP*SN*4
    {
        const float4* gt = (const float4*)(targets + (size_t)b * SN * 11);
        #pragma unroll
        for (int t = 0; t < 11; ++t) ((float4*)tmpT)[lane + 64 * t] = gt[lane + 64 * t];
    }
    __syncthreads();

    // ---- compact valid GT rows (ascending) via ballot prefix ----
    int ngt = 0;
    #pragma unroll
    for (int s = 0; s < 4; ++s) {
        int   pos = s * 64 + lane;
        float tv  = tmpT[pos * 11 + 10];
        sVal[pos] = tv;
        bool  val = tv > 0.5f;
        unsigned long long m = __ballot(val);
        if (val) {
            int r = ngt + (int)__popcll(m & ((1ull << lane) - 1ull));
            #pragma unroll
            for (int d = 0; d < 10; ++d) sRowC[r * 10 + d] = tmpT[pos * 11 + d];
        }
        ngt += (int)__popcll(m);
    }
    __syncthreads();   // tmpT dead; sCost reusable for cost rows

    // Distributed state: column 4L+s and row 4L+s live in lane L slot s.
    float v0 = 0.f, v1 = 0.f, v2 = 0.f, v3 = 0.f;    // column duals
    int   rv0 = -1, rv1 = -1, rv2 = -1, rv3 = -1;    // row4col
    int   cr0 = -1, cr1 = -1, cr2 = -1, cr3 = -1;    // col4row
    int   p0 = -1, p1 = -1, p2 = -1, p3 = -1;        // path
    float sc0 = 0.f, sc1 = 0.f, sc2 = 0.f, sc3 = 0.f;
    int   nfree = 0;

    // ---- fused pass: compute+cache cost rows, greedy row-reduction init ----
    for (int r = 0; r < ngt; ++r) {
        float gc[10];
        #pragma unroll
        for (int d = 0; d < 10; ++d) gc[d] = sRowC[r * 10 + d];
        float4 cc;
        cc.x = costf(prf +  0, gc);
        cc.y = costf(prf + 10, gc);
        cc.z = costf(prf + 20, gc);
        cc.w = costf(prf + 30, gc);
        if (r < CAP) ((float4*)sCost)[r * 64 + lane] = cc;

        unsigned q0 = f2k(cc.x), q1 = f2k(cc.y), q2 = f2k(cc.z), q3 = f2k(cc.w);
        unsigned bk = q0; int bs = 0;
        if (q1 < bk) { bk = q1; bs = 1; }
        if (q2 < bk) { bk = q2; bs = 2; }
        if (q3 < bk) { bk = q3; bs = 3; }
        unsigned mk = bk;
        DPP_MIN(mk, 0x111); DPP_MIN(mk, 0x112); DPP_MIN(mk, 0x114); DPP_MIN(mk, 0x118);
        DPP_MIN(mk, 0x142); DPP_MIN(mk, 0x143);
        unsigned minK = (unsigned)__builtin_amdgcn_readlane((int)mk, 63);
        unsigned long long mm = __ballot(bk == minK);
        int lm   = __builtin_ctzll(mm);
        int slot = __builtin_amdgcn_readlane(bs, lm);
        float minv = k2f(minK);
        if (lane == 0) sU[r] = minv;                 // u[r] = row minimum (feasible dual)

        int rn = __builtin_amdgcn_readlane(sel4(rv0, rv1, rv2, rv3, slot), lm);
        if (rn < 0) {
            // claim column bj = 4*lm+slot for row r
            bool own = (lane == lm);
            switch (slot) {
                case 0:  if (own) rv0 = r; break;
                case 1:  if (own) rv1 = r; break;
                case 2:  if (own) rv2 = r; break;
                default: if (own) rv3 = r; break;
            }
            int sr = r & 3, lr = r >> 2;
            bool ownr = (lane == lr);
            int bj = lm * 4 + slot;
            switch (sr) {
                case 0:  if (ownr) cr0 = bj; break;
                case 1:  if (ownr) cr1 = bj; break;
                case 2:  if (ownr) cr2 = bj; break;
                default: if (ownr) cr3 = bj; break;
            }
        } else {
            if (lane == 0) sFree[nfree] = r;
            nfree++;
        }
    }
    __syncthreads();

    // ---- shortest augmenting path for each remaining free row ----
    for (int fi = 0; fi < nfree; ++fi) {
        const int cur = sFree[fi];
        unsigned k0 = KINF, k1 = KINF, k2 = KINF, k3 = KINF;
        int   scm  = 0;
        float minv = 0.f;
        int   i    = cur;
        int   sink;

        for (;;) {
            float4 cw;
            if (i < CAP) {
                cw = ((const float4*)sCost)[i * 64 + lane];
            } else {
                float gc[10];
                #pragma unroll
                for (int d = 0; d < 10; ++d) gc[d] = sRowC[i * 10 + d];
                cw.x = costf(prf +  0, gc);
                cw.y = costf(prf + 10, gc);
                cw.z = costf(prf + 20, gc);
                cw.w = costf(prf + 30, gc);
            }
            float ui = sU[i];

            #define RELAX(S, CS, KS, PS, VS)                                     \
            {                                                                    \
                float rr = ((minv + CS) - ui) - VS;                              \
                unsigned kr = f2k(rr);                                           \
                bool upd = (kr < KS) && !((scm >> S) & 1);                       \
                if (upd) { KS = kr; PS = i; }                                    \
            }
            RELAX(0, cw.x, k0, p0, v0)
            RELAX(1, cw.y, k1, p1, v1)
            RELAX(2, cw.z, k2, p2, v2)
            RELAX(3, cw.w, k3, p3, v3)
            #undef RELAX

            unsigned bk = k0 < k1 ? k0 : k1;
            unsigned bc = k2 < k3 ? k2 : k3;
            if (bc < bk) bk = bc;
            DPP_MIN(bk, 0x111); DPP_MIN(bk, 0x112); DPP_MIN(bk, 0x114); DPP_MIN(bk, 0x118);
            DPP_MIN(bk, 0x142); DPP_MIN(bk, 0x143);
            unsigned minK = (unsigned)__builtin_amdgcn_readlane((int)bk, 63);

            // winner = lowest column with key==minK (first-occurrence tie-break)
            unsigned long long m0 = __ballot(k0 == minK);
            unsigned long long m1 = __ballot(k1 == minK);
            unsigned long long m2 = __ballot(k2 == minK);
            unsigned long long m3 = __ballot(k3 == minK);
            int l0 = m0 ? __builtin_ctzll(m0) : 64;
            int l1 = m1 ? __builtin_ctzll(m1) : 64;
            int l2 = m2 ? __builtin_ctzll(m2) : 64;
            int l3 = m3 ? __builtin_ctzll(m3) : 64;
            int lm  = l0 < l1 ? l0 : l1;
            int lmb = l2 < l3 ? l2 : l3;
            if (lmb < lm) lm = lmb;
            int slot = (l0 == lm) ? 0 : (l1 == lm) ? 1 : (l2 == lm) ? 2 : 3;
            int bj   = lm * 4 + slot;

            minv = k2f(minK);
            int rn = __builtin_amdgcn_readlane(sel4(rv0, rv1, rv2, rv3, slot), lm);
            if (rn < 0) { sink = bj; break; }
            i = rn;

            bool own = (lane == lm);
            switch (slot) {
                case 0:  if (own) { scm |= 1; k0 = KMAX; sc0 = minv; } break;
                case 1:  if (own) { scm |= 2; k1 = KMAX; sc1 = minv; } break;
                case 2:  if (own) { scm |= 4; k2 = KMAX; sc2 = minv; } break;
                default: if (own) { scm |= 8; k3 = KMAX; sc3 = minv; } break;
            }
        }

        // ---- dual updates (before augmentation) ----
        if (lane == 0) sU[cur] += minv;
        if (scm & 1) { sU[rv0] += minv - sc0; v0 += sc0 - minv; }
        if (scm & 2) { sU[rv1] += minv - sc1; v1 += sc1 - minv; }
        if (scm & 4) { sU[rv2] += minv - sc2; v2 += sc2 - minv; }
        if (scm & 8) { sU[rv3] += minv - sc3; v3 += sc3 - minv; }

        // ---- augment: wave-uniform register walk ----
        int j = sink;
        for (;;) {
            int sj = j & 3, lj = j >> 2;
            int i2 = __builtin_amdgcn_readlane(sel4(p0, p1, p2, p3, sj), lj);
            bool ownj = (lane == lj);
            switch (sj) {
                case 0:  if (ownj) rv0 = i2; break;
                case 1:  if (ownj) rv1 = i2; break;
                case 2:  if (ownj) rv2 = i2; break;
                default: if (ownj) rv3 = i2; break;
            }
            int si = i2 & 3, li = i2 >> 2;
            int tmp = __builtin_amdgcn_readlane(sel4(cr0, cr1, cr2, cr3, si), li);
            bool owni = (lane == li);
            switch (si) {
                case 0:  if (owni) cr0 = j; break;
                case 1:  if (owni) cr1 = j; break;
                case 2:  if (owni) cr2 = j; break;
                default: if (owni) cr3 = j; break;
            }
            j = tmp;
            if (i2 == cur) break;
        }
        __syncthreads();
    }

    // ---- loss: dump pred regs to LDS scratch (sCost reused), then gather ----
    __syncthreads();
    float* sPredScr = sCost;
    #pragma unroll
    for (int t = 0; t < 10; ++t) ((float4*)sPredScr)[lane * 10 + t] = ((float4*)prf)[t];
    __syncthreads();

    float coordv = 0.f, widthv = 0.f;
    #pragma unroll
    for (int s = 0; s < 4; ++s) {
        int r = lane * 4 + s;
        if (r < ngt) {
            int p = (s == 0) ? cr0 : (s == 1) ? cr1 : (s == 2) ? cr2 : cr3;
            const float* pp = &sPredScr[p * 10];
            const float* gg = &sRowC[r * 10];
            float c = 0.f;
            #pragma unroll
            for (int d = 0; d < 8; ++d) c += fabsf(pp[d] - gg[d]);
            coordv += c;
            widthv += fabsf(pp[8] - gg[8]) + fabsf(pp[9] - gg[9]);
        }
    }
    float bces = 0.f;
    {
        const float4 pv = ((const float4*)(pred_validity + (size_t)b * SN))[lane];
        const float pvs[4] = {pv.x, pv.y, pv.z, pv.w};
        #pragma unroll
        for (int s = 0; s < 4; ++s) {
            float t   = sVal[lane * 4 + s];
            float p   = pvs[s];
            float lp  = logf(p);       if (lp  < -100.f) lp  = -100.f;
            float l1p = logf(1.f - p); if (l1p < -100.f) l1p = -100.f;
            bces += -(t * lp + (1.f - t) * l1p);
        }
    }
    #pragma unroll
    for (int m = 1; m <= 32; m <<= 1) {
        coordv += __shfl_xor(coordv, m, 64);
        widthv += __shfl_xor(widthv, m, 64);
        bces   += __shfl_xor(bces,   m, 64);
    }
    if (lane == 0) {
        float bcem = bces / (float)SN;
        float lb = (ngt > 0)
                 ? (5.f * coordv / (8.f * (float)ngt) + widthv / (2.f * (float)ngt) + bcem)
                 : bcem;
        loss_b[b] = lb;
    }
}

__global__ __launch_bounds__(64) void detr_finalize_kernel(
    const float* __restrict__ loss_b, float* __restrict__ out)
{
    int lane = threadIdx.x;
    float x = (lane < BN) ? loss_b[lane] : 0.f;
    #pragma unroll
    for (int m = 1; m <= 32; m <<= 1) x += __shfl_xor(x, m, 64);
    if (lane == 0) out[0] = x / (float)BN;
}

extern "C" void kernel_launch(void* const* d_in, const int* in_sizes, int n_in,
                              void* d_out, int out_size, void* d_ws, size_t ws_size,
                              hipStream_t stream) {
    const float* pred_strokes  = (const float*)d_in[0];
    const float* pred_validity = (const float*)d_in[1];
    const float* targets       = (const float*)d_in[2];
    float* out    = (float*)d_out;
    float* loss_b = (float*)d_ws;

    detr_match_kernel<<<BN, 64, 0, stream>>>(pred_strokes, pred_validity, targets, loss_b);
    detr_finalize_kernel<<<1, 64, 0, stream>>>(loss_b, out);
}